// Round 3
// baseline (286.870 us; speedup 1.0000x reference)
//
#include <hip/hip_runtime.h>
#include <stdint.h>

// Problem constants (LieAction): B=16384, K=64, M=6, NUM_ACTIONS=16
// All float tensors are fp32 per the reference; act is int32.
#define BATCH 16384
#define KSUB 64
#define MDIM 6
#define MM 36            // M*M floats per (b,k) block
#define NACT 16
#define F4PB 9           // float4 per block (36 floats)
#define BLK 256          // (b,k)-blocks per workgroup == threads per workgroup
#define LDSPITCH 37      // 36 floats + 1 pad (odd pitch -> ~conflict-free reads)

// Kernel 1: R[a][k] = expm( act_params[a,k] * (L_k - L_k^T) ), fp32, Taylor n<=10.
// ||A||_inf <= ~0.05 (params ~ 1e-3 * N(0,1)) -> truncation error ~1e-12.
__global__ void expm_table_kernel(const float* __restrict__ act_params, // [NACT,KSUB] f32
                                  const float* __restrict__ basis,      // [KSUB,36] f32
                                  float* __restrict__ Rtab)             // [NACT*KSUB,36] f32
{
    int gid = blockIdx.x * blockDim.x + threadIdx.x;
    if (gid >= NACT * KSUB) return;
    int a = gid / KSUB;
    int k = gid - a * KSUB;

    float L[MM];
#pragma unroll
    for (int i = 0; i < MM; ++i) L[i] = basis[k * MM + i];
    float p = act_params[a * KSUB + k];

    float A[MM];
#pragma unroll
    for (int i = 0; i < MDIM; ++i)
#pragma unroll
        for (int j = 0; j < MDIM; ++j)
            A[i * MDIM + j] = p * (L[i * MDIM + j] - L[j * MDIM + i]);

    float E[MM], T[MM];
#pragma unroll
    for (int i = 0; i < MM; ++i) { E[i] = 0.f; T[i] = 0.f; }
#pragma unroll
    for (int i = 0; i < MDIM; ++i) { E[i * MDIM + i] = 1.f; T[i * MDIM + i] = 1.f; }

    for (int n = 1; n <= 10; ++n) {
        float Tn[MM];
        float inv = 1.0f / (float)n;
#pragma unroll
        for (int i = 0; i < MDIM; ++i)
#pragma unroll
            for (int l = 0; l < MDIM; ++l) {
                float s = 0.f;
#pragma unroll
                for (int j = 0; j < MDIM; ++j)
                    s += A[i * MDIM + j] * T[j * MDIM + l];
                Tn[i * MDIM + l] = s * inv;
            }
#pragma unroll
        for (int i = 0; i < MM; ++i) { T[i] = Tn[i]; E[i] += Tn[i]; }
    }
#pragma unroll
    for (int i = 0; i < MM; ++i) Rtab[gid * MM + i] = E[i];
}

// Kernel 2: out[b,k] = R[act[b],k] @ G[b,k]  (6x6 @ 6x6, fp32)
// Coalesced global IO (float4 = 16B/lane) via LDS transpose; one block per thread.
// Per wg: 256 blocks * 9 float4 = 2304 float4 = 9 iters * 256 lanes exactly.
__global__ __launch_bounds__(BLK) void apply_kernel(
    const float4* __restrict__ gf4,          // B*K*9 float4
    const int* __restrict__ act,             // [B] int32
    const float* __restrict__ Rtab,          // [NACT*KSUB*36] f32
    float4* __restrict__ out4)               // B*K*9 float4
{
    __shared__ float lds[BLK * LDSPITCH];
    const int tid = threadIdx.x;
    const size_t base4 = (size_t)blockIdx.x * (BLK * F4PB);   // float4 units

    // stage: 9 x 256 float4 loads, scatter into pitch-37 LDS rows
#pragma unroll
    for (int i = 0; i < F4PB; ++i) {
        int p4 = tid + i * BLK;          // float4 index within wg, 0..2303
        float4 v = gf4[base4 + p4];
        int n = p4 / F4PB;               // block row 0..255
        int j = (p4 - n * F4PB) * 4;     // float offset within row, 0..32
        float* row = &lds[n * LDSPITCH + j];
        row[0] = v.x; row[1] = v.y; row[2] = v.z; row[3] = v.w;
    }
    __syncthreads();

    const int nblk = blockIdx.x * BLK + tid;
    const int b = nblk >> 6;          // / KSUB
    const int k = nblk & 63;          // % KSUB
    const int a = act[b];

    // load R (36 f32; offset multiple of 144B -> 16B aligned) as 9 float4
    float Rv[MM];
    const float4* R4 = (const float4*)(Rtab + (a * KSUB + k) * MM);
#pragma unroll
    for (int q = 0; q < F4PB; ++q) {
        float4 v = R4[q];
        Rv[4 * q + 0] = v.x; Rv[4 * q + 1] = v.y;
        Rv[4 * q + 2] = v.z; Rv[4 * q + 3] = v.w;
    }

    // this thread's G from its own LDS row (lane stride 37: 2-way aliasing = free)
    float G[MM];
#pragma unroll
    for (int j = 0; j < MM; ++j) G[j] = lds[tid * LDSPITCH + j];

    // O = R @ G  (fp32)
    float O[MM];
#pragma unroll
    for (int i = 0; i < MM; ++i) O[i] = 0.f;
#pragma unroll
    for (int j = 0; j < MDIM; ++j)
#pragma unroll
        for (int i = 0; i < MDIM; ++i) {
            float r = Rv[i * MDIM + j];
#pragma unroll
            for (int l = 0; l < MDIM; ++l)
                O[i * MDIM + l] = fmaf(r, G[j * MDIM + l], O[i * MDIM + l]);
        }

    // write O back into own LDS row (row tid touched only by thread tid here)
#pragma unroll
    for (int j = 0; j < MM; ++j) lds[tid * LDSPITCH + j] = O[j];
    __syncthreads();

    // coalesced store: gather from pitch-37 rows, 9 x 256 float4
#pragma unroll
    for (int i = 0; i < F4PB; ++i) {
        int p4 = tid + i * BLK;
        int n = p4 / F4PB;
        int j = (p4 - n * F4PB) * 4;
        const float* row = &lds[n * LDSPITCH + j];
        float4 v;
        v.x = row[0]; v.y = row[1]; v.z = row[2]; v.w = row[3];
        out4[base4 + p4] = v;
    }
}

extern "C" void kernel_launch(void* const* d_in, const int* in_sizes, int n_in,
                              void* d_out, int out_size, void* d_ws, size_t ws_size,
                              hipStream_t stream) {
    const float* gf    = (const float*)d_in[0];  // group_feats f32 [B, K*36]
    const int*   act   = (const int*)d_in[1];    // [B] int32
    const float* ap    = (const float*)d_in[2];  // act_params f32 [16,64]
    const float* basis = (const float*)d_in[3];  // lie_alg_basis f32 [64,36]

    float* Rtab = (float*)d_ws;   // needs 16*64*36*4 = 147456 B of ws

    expm_table_kernel<<<4, 256, 0, stream>>>(ap, basis, Rtab);

    const int nwg = (BATCH * KSUB) / BLK;   // 4096
    apply_kernel<<<nwg, BLK, 0, stream>>>((const float4*)gf, act, Rtab,
                                          (float4*)d_out);
}

// Round 4
// 269.114 us; speedup vs baseline: 1.0660x; 1.0660x over previous
//
#include <hip/hip_runtime.h>
#include <stdint.h>

// Problem constants (LieAction): B=16384, K=64, M=6, NUM_ACTIONS=16
// All float tensors fp32; act int32.
#define BATCH 16384
#define KSUB 64
#define MDIM 6
#define MM 36            // floats per (b,k) block
#define NACT 16
#define F4PB 9           // float4 per block
#define WGT 64           // threads per wg == blocks per wg (single wave, no convoy)
#define LDSPITCH 37      // 36 + 1 pad (odd pitch -> compute reads 2-way aliased = free)

typedef float f32x4 __attribute__((ext_vector_type(4)));

// Kernel 1: R[a][k] = expm( act_params[a,k] * (L_k - L_k^T) ), fp32 Taylor n<=10.
// ||A||_inf <~ 0.05 -> truncation error ~1e-12.
__global__ void expm_table_kernel(const float* __restrict__ act_params, // [NACT,KSUB]
                                  const float* __restrict__ basis,      // [KSUB,36]
                                  float* __restrict__ Rtab)             // [NACT*KSUB,36]
{
    int gid = blockIdx.x * blockDim.x + threadIdx.x;
    if (gid >= NACT * KSUB) return;
    int a = gid / KSUB;
    int k = gid - a * KSUB;

    float L[MM];
#pragma unroll
    for (int i = 0; i < MM; ++i) L[i] = basis[k * MM + i];
    float p = act_params[a * KSUB + k];

    float A[MM];
#pragma unroll
    for (int i = 0; i < MDIM; ++i)
#pragma unroll
        for (int j = 0; j < MDIM; ++j)
            A[i * MDIM + j] = p * (L[i * MDIM + j] - L[j * MDIM + i]);

    float E[MM], T[MM];
#pragma unroll
    for (int i = 0; i < MM; ++i) { E[i] = 0.f; T[i] = 0.f; }
#pragma unroll
    for (int i = 0; i < MDIM; ++i) { E[i * MDIM + i] = 1.f; T[i * MDIM + i] = 1.f; }

    for (int n = 1; n <= 10; ++n) {
        float Tn[MM];
        float inv = 1.0f / (float)n;
#pragma unroll
        for (int i = 0; i < MDIM; ++i)
#pragma unroll
            for (int l = 0; l < MDIM; ++l) {
                float s = 0.f;
#pragma unroll
                for (int j = 0; j < MDIM; ++j)
                    s += A[i * MDIM + j] * T[j * MDIM + l];
                Tn[i * MDIM + l] = s * inv;
            }
#pragma unroll
        for (int i = 0; i < MM; ++i) { T[i] = Tn[i]; E[i] += Tn[i]; }
    }
#pragma unroll
    for (int i = 0; i < MM; ++i) Rtab[gid * MM + i] = E[i];
}

// Kernel 2: out[b,k] = R[act[b],k] @ G[b,k]  (6x6 @ 6x6, fp32)
// One 64-thread wg per batch row b: thread k owns block (b,k).
// b = blockIdx.x is wg-uniform -> act[b] is an s_load; R rows are one
// contiguous 9.2 KB lane-strided chunk. Single wave per wg -> barriers are
// wave-local (no inter-wave convoying); 9.5 KB LDS -> ~16 independent
// waves/CU to keep the memory pipe continuously busy.
__global__ __launch_bounds__(WGT, 4) void apply_kernel(
    const f32x4* __restrict__ gf4,           // B*K*9 float4
    const int* __restrict__ act,             // [B] int32
    const float* __restrict__ Rtab,          // [NACT*KSUB*36] f32
    f32x4* __restrict__ out4)                // B*K*9 float4
{
    __shared__ float lds[WGT * LDSPITCH];    // 9472 B
    const int tid = threadIdx.x;
    const int b = blockIdx.x;
    const size_t base4 = (size_t)b * (WGT * F4PB);   // float4 units

    // R prefetch first (independent of staging): lane tid -> row (act[b]*64+tid)
    const int a = act[b];                    // wg-uniform -> scalar load
    const f32x4* R4 = (const f32x4*)(Rtab + (size_t)((a << 6) + tid) * MM);
    f32x4 rv[F4PB];
#pragma unroll
    for (int q = 0; q < F4PB; ++q) rv[q] = R4[q];

    // stage 64 blocks (576 float4) coalesced, nontemporal (streamed once)
#pragma unroll
    for (int i = 0; i < F4PB; ++i) {
        int p4 = tid + (i << 6);             // 0..575
        f32x4 v = __builtin_nontemporal_load(&gf4[base4 + p4]);
        int n = p4 / F4PB;                   // block row 0..63
        int j = (p4 - n * F4PB) * 4;         // 0..32
        float* row = &lds[n * LDSPITCH + j];
        row[0] = v.x; row[1] = v.y; row[2] = v.z; row[3] = v.w;
    }
    __syncthreads();                         // single-wave: cheap

    // this thread's G from its own LDS row (stride 37: 2-way aliasing = free)
    float G[MM];
#pragma unroll
    for (int j = 0; j < MM; ++j) G[j] = lds[tid * LDSPITCH + j];

    // O = R @ G (fp32)
    float Rv[MM];
#pragma unroll
    for (int q = 0; q < F4PB; ++q) {
        Rv[4 * q + 0] = rv[q].x; Rv[4 * q + 1] = rv[q].y;
        Rv[4 * q + 2] = rv[q].z; Rv[4 * q + 3] = rv[q].w;
    }
    float O[MM];
#pragma unroll
    for (int i = 0; i < MM; ++i) O[i] = 0.f;
#pragma unroll
    for (int j = 0; j < MDIM; ++j)
#pragma unroll
        for (int i = 0; i < MDIM; ++i) {
            float r = Rv[i * MDIM + j];
#pragma unroll
            for (int l = 0; l < MDIM; ++l)
                O[i * MDIM + l] = fmaf(r, G[j * MDIM + l], O[i * MDIM + l]);
        }

    __syncthreads();                         // staged input fully consumed
    // write O to own row, then coalesced gather-store
#pragma unroll
    for (int j = 0; j < MM; ++j) lds[tid * LDSPITCH + j] = O[j];
    __syncthreads();

#pragma unroll
    for (int i = 0; i < F4PB; ++i) {
        int p4 = tid + (i << 6);
        int n = p4 / F4PB;
        int j = (p4 - n * F4PB) * 4;
        const float* row = &lds[n * LDSPITCH + j];
        f32x4 v;
        v.x = row[0]; v.y = row[1]; v.z = row[2]; v.w = row[3];
        __builtin_nontemporal_store(v, &out4[base4 + p4]);
    }
}

extern "C" void kernel_launch(void* const* d_in, const int* in_sizes, int n_in,
                              void* d_out, int out_size, void* d_ws, size_t ws_size,
                              hipStream_t stream) {
    const float* gf    = (const float*)d_in[0];  // group_feats f32 [B, K*36]
    const int*   act   = (const int*)d_in[1];    // [B] int32
    const float* ap    = (const float*)d_in[2];  // act_params f32 [16,64]
    const float* basis = (const float*)d_in[3];  // lie_alg_basis f32 [64,36]

    float* Rtab = (float*)d_ws;   // 16*64*36*4 = 147456 B of ws

    expm_table_kernel<<<16, 64, 0, stream>>>(ap, basis, Rtab);

    apply_kernel<<<BATCH, WGT, 0, stream>>>((const f32x4*)gf, act, Rtab,
                                            (f32x4*)d_out);
}